// Round 13
// baseline (933.861 us; speedup 1.0000x reference)
//
#include <hip/hip_runtime.h>
#include <stdint.h>

#define TT 1024
#define HB 256
#define NE 48                       // per-row entry capacity (flag if exceeded)
#define NE2 24                      // per-lane slots (2 lanes/row)
#define O1 67108864u                // B*T*H
#define O2 (67108864u + 524288u)    // + B*T*2

__device__ __forceinline__ uint32_t rotl32(uint32_t x, uint32_t r){ return (x<<r)|(x>>(32u-r)); }

#define RND(r) { x0+=x1; x1=rotl32(x1,(r)); x1^=x0; }
__device__ __forceinline__ void tf2x32(uint32_t k0,uint32_t k1,uint32_t& x0,uint32_t& x1){
  const uint32_t ks2 = 0x1BD11BDAu ^ k0 ^ k1;
  x0 += k0; x1 += k1;
  RND(13) RND(15) RND(26) RND(6)  x0+=k1;  x1+=ks2+1u;
  RND(17) RND(29) RND(16) RND(24) x0+=ks2; x1+=k0+2u;
  RND(13) RND(15) RND(26) RND(6)  x0+=k0;  x1+=k1+3u;
  RND(17) RND(29) RND(16) RND(24) x0+=k1;  x1+=ks2+4u;
  RND(13) RND(15) RND(26) RND(6)  x0+=ks2; x1+=k0+5u;
}
#undef RND

// uniform(-0.99999994,1) -> sqrt(2)*erfinv (Giles poly, HW log) -> *0.05*0.5
__device__ __forceinline__ float bits_to_noise(uint32_t bits){
  float f = __uint_as_float((bits>>9) | 0x3F800000u) - 1.0f;
  const float lo = -0.99999994f;
  float x = fmaxf(fmaf(f, 1.99999994f, lo), lo);
  float m = (1.0f - x) * (1.0f + x);              // 1-x^2, cancellation-free
  float w = -0.69314718056f * __log2f(m);
  float p;
  if (w < 5.0f){
    w -= 2.5f;
    p = 2.81022636e-08f;
    p = fmaf(p, w, 3.43273939e-07f);
    p = fmaf(p, w, -3.5233877e-06f);
    p = fmaf(p, w, -4.39150654e-06f);
    p = fmaf(p, w, 0.00021858087f);
    p = fmaf(p, w, -0.00125372503f);
    p = fmaf(p, w, -0.00417768164f);
    p = fmaf(p, w, 0.246640727f);
    p = fmaf(p, w, 1.50140941f);
  } else {
    w = __fsqrt_rn(w) - 3.0f;
    p = -0.000200214257f;
    p = fmaf(p, w, 0.000100950558f);
    p = fmaf(p, w, 0.00134934322f);
    p = fmaf(p, w, -0.00367342844f);
    p = fmaf(p, w, 0.00573950773f);
    p = fmaf(p, w, -0.0076224613f);
    p = fmaf(p, w, 0.00943887047f);
    p = fmaf(p, w, 1.00167406f);
    p = fmaf(p, w, 2.83297682f);
  }
  return 0.035355339059f * (p * x);   // sqrt(2)*0.05*0.5
}

__global__ void init_flags(uint32_t* flags){
  if (flags) { flags[0]=0u; flags[1]=0u; }
}

__global__ void check_kernel(float* out, const uint32_t* flags){
  uint32_t a0=0u, a1=0u;                 tf2x32(0u,0u,a0,a1);
  uint32_t b0=0xffffffffu, b1=0xffffffffu; tf2x32(0xffffffffu,0xffffffffu,b0,b1);
  uint32_t c0=0x243f6a88u, c1=0x85a308d3u; tf2x32(0x13198a2eu,0x03707344u,c0,c1);
  if (!(a0==0x6b200159u && a1==0x99ba4efeu)) out[0] = 1e30f;
  if (!(b0==0x1cb996fcu && b1==0xbb002be7u)) out[1] = 2e30f;
  if (!(c0==0xc4923a9cu && c1==0x483df7a0u)) out[2] = 3e30f;
  if (flags && flags[0]) out[5] = 6e30f;   // row entry-count overflow
}

struct StageBufs {                       // init-only staging
  float    ew[HB][NE];                   // 48 KB
  uint16_t ei[HB][NE];                   // 24 KB
};
struct RunBufs {                         // main-loop buffers (OVERWRITE staging)
  float xbuf[TT*2];                      // 8 KB
  float hstage[16][HB];                  // 16 KB (rank-indexed)
  float nbuf[4][HB];                     // 4 KB  (rank-indexed)
  float tbuf[2][HB];                     // 2 KB  (rank-indexed)
  float obuf[16][2];                     // output ring
};

__launch_bounds__(1024, 4)
__global__ void rnn_kernel(const float* __restrict__ input_signal, // [B,T,2]
                           const float* __restrict__ hidden0,      // [B,H]
                           const float* __restrict__ w_in,         // [H,2]
                           const float* __restrict__ w_out,        // [2,H]
                           const float* __restrict__ abs_w0,       // [H,H]
                           const float* __restrict__ w_sign,       // [H,H]
                           const float* __restrict__ is_con,       // [H,H]
                           float* __restrict__ out,
                           uint32_t* __restrict__ flags)
{
  __shared__ union { StageBufs stage; RunBufs run; } sh;   // 72 KB, aliased
  __shared__ int   cnts[HB];
  __shared__ int   rankinv[HB];          // rank -> row
  __shared__ int   rof4[HB];             // row -> rank*4 (byte offset)
  __shared__ float wot0[HB], wot1[HB];   // w_out in rank order

  const int tid = threadIdx.x;
  const int b   = blockIdx.x;
  const bool gw = (tid < 512);           // waves 0-7 gather; 8-15 noise/outproj

  // ---- P0: per-row counts ----
  if (tid < HB){
    int c = 0;
    const float* ic = is_con + tid*HB;
    for (int k = 0; k < HB; k += 4){
      float4 c4 = *(const float4*)(ic + k);
      c += (c4.x>0.f)+(c4.y>0.f)+(c4.z>0.f)+(c4.w>0.f);
    }
    cnts[tid] = c;
    if (c > NE && flags) flags[0] = 1u;
  }
  __syncthreads();

  // ---- P1: ranks (descending count, tie by index) ----
  if (tid < HB){
    int myc = cnts[tid], r = 0;
    for (int k = 0; k < HB; ++k){
      int ck = cnts[k];
      r += (int)((ck > myc) || (ck == myc && k < tid));
    }
    rankinv[r] = tid;
    rof4[tid]  = r << 2;
  }
  __syncthreads();

  // ---- P2: build staged entry lists + wot scatter ----
  if (tid < HB){
    const int j = tid;
    const float* ic = is_con + j*HB;
    const float* aw = abs_w0 + j*HB;
    const float* ws = w_sign + j*HB;
    int n = 0;
    for (int k = 0; k < HB; ++k){
      if (ic[k] > 0.f && n < NE){
        sh.stage.ew[j][n] = ws[k]*aw[k];
        sh.stage.ei[j][n] = (uint16_t)rof4[k];
        ++n;
      }
    }
    for (int s = n; s < NE; ++s){ sh.stage.ew[j][s] = 0.f; sh.stage.ei[j][s] = (uint16_t)rof4[j]; }
    wot0[rof4[j]>>2] = w_out[j];
    wot1[rof4[j]>>2] = w_out[HB + j];
  }
  __syncthreads();

  // ---- P3: pack entries to REGISTERS (staging dies after this phase) ----
  float    pwv[NE2];                     // f32 weights (24 regs)
  uint32_t piv[NE2/2];                   // 2 u16 byte-offsets per reg (12 regs)
  int trip = 0, row = 0, q = 0, rr = 0;
  float h = 0.f, wi0 = 0.f, wi1 = 0.f;
  float4 wo0 = {0,0,0,0}, wo1 = {0,0,0,0};
  uint32_t bj = 0u;
  const int j0 = (tid & 127) << 1;       // flush columns (all threads)
  const int rf0 = rof4[j0], rf1 = rof4[j0+1];
  if (gw){
    rr = tid >> 1; q = tid & 1;
    row = rankinv[rr];
    int c = cnts[row]; if (c > NE) c = NE;
    uint32_t pad = (uint32_t)rof4[row];
    uint32_t cur = 0u;
    #pragma unroll
    for (int s = 0; s < NE2; ++s){
      int idx = 2*s + q;
      float w = 0.f; uint32_t o = pad;
      if (idx < c){ w = sh.stage.ew[row][idx]; o = sh.stage.ei[row][idx]; }
      pwv[s] = w;
      if (s & 1) piv[s>>1] = cur | (o << 16); else cur = o;
    }
    trip = __builtin_amdgcn_readfirstlane((c + 1) >> 1);  // lane0 = wave max (sorted)
    h   = hidden0[b*HB + row];
    wi0 = w_in[row*2]; wi1 = w_in[row*2 + 1];
  } else {
    int m2 = tid - 512;
    bj = (uint32_t)b*256u + (uint32_t)rankinv[m2 >> 1];
    if (m2 < 128){
      int lam = m2 & 63;
      wo0 = *(const float4*)(wot0 + lam*4);
      wo1 = *(const float4*)(wot1 + lam*4);
    }
  }
  __syncthreads();                       // all staging reads complete

  // ---- P4: overwrite staging with runtime buffers (forces reg residency) ----
  {
    const float* xg = input_signal + (uint64_t)b*TT*2;
    *(float2*)(sh.run.xbuf + tid*2) = *(const float2*)(xg + tid*2);
  }
  if (gw){
    if (q == 0) sh.run.tbuf[0][rr] = 1.0f - 2.0f/(__expf(2.0f*h) + 1.0f);
  } else {
    int m2 = tid - 512, rn = m2 >> 1, qn = m2 & 1;
    if (qn == 0){
      uint32_t x0 = 0u, x1 = bj;
      tf2x32(0u, 42u, x0, x1);
      sh.run.nbuf[0][rn] = bits_to_noise(x0 ^ x1);
    }
  }
  float* hrow = out + (uint64_t)b*TT*HB;
  float* orow = out + O1 + (uint64_t)b*TT*2;
  __syncthreads();

  // ---- main loop: one barrier per step; global stores only every 8th step ----
  for (int t = 0; t < TT; ++t){
    const int par = t & 1;
    if (gw){
      const char* tb = (const char*)(&sh.run.tbuf[par][0]);
      float y0 = 0.f, y1 = 0.f;
      #pragma unroll
      for (int s = 0; s < NE2; s += 2){
        if (s < trip){                             // wave-uniform guard
          uint32_t pa = piv[s>>1];
          y0 = fmaf(pwv[s],   *(const float*)(tb + (pa & 0xFFFFu)), y0);
          y1 = fmaf(pwv[s+1], *(const float*)(tb + (pa >> 16)),     y1);
        }
      }
      float y = y0 + y1;
      y += __shfl_xor(y, 1, 64);                   // combine row halves
      if (q == 0){
        float nz = sh.run.nbuf[t&3][rr];
        float2 xv = *(const float2*)(sh.run.xbuf + t*2);
        float u = fmaf(xv.x, wi0, xv.y*wi1);
        h = fmaf(0.25f, u + y, 0.75f*h) + nz;
        sh.run.hstage[t&15][rr] = h;
        sh.run.tbuf[par^1][rr] = 1.0f - 2.0f/(__expf(2.0f*h) + 1.0f);
      }
    } else {
      int m2 = tid - 512;
      if (!(t & 1)){                               // even t: noise for t+1, t+2
        int tv = t + 1 + (m2 & 1);
        if (tv < TT){
          uint32_t x0 = 0u, x1 = (uint32_t)tv*65536u + bj;
          tf2x32(0u, 42u, x0, x1);
          sh.run.nbuf[tv&3][m2>>1] = bits_to_noise(x0 ^ x1);
        }
      } else if (m2 < 128){                        // odd t: outproj o(t-2), o(t-1) -> LDS
        int tau = t - 2 + (m2 >> 6);
        if (tau >= 0){
          int lam = m2 & 63;
          float4 hv = *(const float4*)(&sh.run.hstage[tau&15][lam*4]);
          float p0 = hv.x*wo0.x + hv.y*wo0.y + hv.z*wo0.z + hv.w*wo0.w;
          float p1 = hv.x*wo1.x + hv.y*wo1.y + hv.z*wo1.z + hv.w*wo1.w;
          #pragma unroll
          for (int d = 1; d < 64; d <<= 1){
            p0 += __shfl_xor(p0, d, 64);
            p1 += __shfl_xor(p1, d, 64);
          }
          if (lam == 0){ sh.run.obuf[tau&15][0] = p0; sh.run.obuf[tau&15][1] = p1; }
        }
      }
    }
    __syncthreads();                               // the one barrier per step

    if ((t & 7) == 7){                             // flush rows t-14..t-7 (slot (t+1)&15
      int s  = tid >> 7;                           //  is outside the window -> race-free)
      int fr = t - 14 + s;
      if (fr >= 0){
        const char* hs = (const char*)(&sh.run.hstage[fr&15][0]);
        float2 v;
        v.x = *(const float*)(hs + rf0);
        v.y = *(const float*)(hs + rf1);
        *(float2*)(hrow + (uint64_t)fr*HB + j0) = v;
      }
      if (tid < 16){                               // o flush from obuf
        int so = tid >> 1, fo = t - 14 + so;
        if (fo >= 0) orow[fo*2 + (tid&1)] = sh.run.obuf[fo&15][tid&1];
      }
    }
  }

  // ---- tail: rows 1017..1023 hrow, o(1017..1022), o(1023), h_last ----
  {
    int s = tid >> 7;
    if (s >= 1){
      int fr = 1016 + s;
      const char* hs = (const char*)(&sh.run.hstage[fr&15][0]);
      float2 v;
      v.x = *(const float*)(hs + rf0);
      v.y = *(const float*)(hs + rf1);
      *(float2*)(hrow + (uint64_t)fr*HB + j0) = v;
    }
  }
  if (tid < 12){
    int s = tid >> 1;
    orow[(1017+s)*2 + (tid&1)] = sh.run.obuf[(1017+s)&15][tid&1];
  }
  if (!gw){
    int m2 = tid - 512;
    if (m2 < 64){
      float4 hv = *(const float4*)(&sh.run.hstage[1023&15][m2*4]);
      float p0 = hv.x*wo0.x + hv.y*wo0.y + hv.z*wo0.z + hv.w*wo0.w;
      float p1 = hv.x*wo1.x + hv.y*wo1.y + hv.z*wo1.z + hv.w*wo1.w;
      #pragma unroll
      for (int d = 1; d < 64; d <<= 1){
        p0 += __shfl_xor(p0, d, 64);
        p1 += __shfl_xor(p1, d, 64);
      }
      if (m2 == 0) *(float2*)(orow + (TT-1)*2) = make_float2(p0, p1);
    }
  }
  if (gw && q == 0) out[O2 + b*HB + row] = h;
}

extern "C" void kernel_launch(void* const* d_in, const int* in_sizes, int n_in,
                              void* d_out, int out_size, void* d_ws, size_t ws_size,
                              hipStream_t stream) {
  const float* input_signal = (const float*)d_in[0];
  const float* hidden       = (const float*)d_in[1];
  const float* w_in         = (const float*)d_in[2];
  const float* w_out        = (const float*)d_in[3];
  const float* abs_w0       = (const float*)d_in[4];
  const float* w_sign       = (const float*)d_in[5];
  const float* is_con       = (const float*)d_in[6];
  float* out = (float*)d_out;
  uint32_t* flags = (ws_size >= 8) ? (uint32_t*)d_ws : nullptr;

  init_flags<<<1, 1, 0, stream>>>(flags);
  rnn_kernel<<<256, 1024, 0, stream>>>(input_signal, hidden, w_in, w_out,
                                       abs_w0, w_sign, is_con, out, flags);
  check_kernel<<<1, 1, 0, stream>>>(out, flags);
}

// Round 14
// 863.397 us; speedup vs baseline: 1.0816x; 1.0816x over previous
//
#include <hip/hip_runtime.h>
#include <stdint.h>

#define TT 1024
#define HB 256
#define NE 48                       // per-row entry capacity (flag if exceeded)
#define NE2 24                      // per-lane slots (2 lanes/row)
#define O1 67108864u                // B*T*H
#define O2 (67108864u + 524288u)    // + B*T*2

__device__ __forceinline__ uint32_t rotl32(uint32_t x, uint32_t r){ return (x<<r)|(x>>(32u-r)); }

#define RND(r) { x0+=x1; x1=rotl32(x1,(r)); x1^=x0; }
__device__ __forceinline__ void tf_h1g(uint32_t k0,uint32_t k1,uint32_t ks2,uint32_t& x0,uint32_t& x1){
  x0 += k0; x1 += k1;
  RND(13) RND(15) RND(26) RND(6)  x0+=k1;  x1+=ks2+1u;
  RND(17) RND(29) RND(16) RND(24) x0+=ks2; x1+=k0+2u;
  RND(13) RND(15) RND(26) RND(6)  x0+=k0;  x1+=k1+3u;
}
__device__ __forceinline__ void tf_h2g(uint32_t k0,uint32_t k1,uint32_t ks2,uint32_t& x0,uint32_t& x1){
  RND(17) RND(29) RND(16) RND(24) x0+=k1;  x1+=ks2+4u;
  RND(13) RND(15) RND(26) RND(6)  x0+=ks2; x1+=k0+5u;
}
__device__ __forceinline__ void tf2x32(uint32_t k0,uint32_t k1,uint32_t& x0,uint32_t& x1){
  const uint32_t ks2 = 0x1BD11BDAu ^ k0 ^ k1;
  tf_h1g(k0,k1,ks2,x0,x1); tf_h2g(k0,k1,ks2,x0,x1);
}
// fixed key (0,42): ks2 = 0x1BD11BDA ^ 42 = 0x1BD11BF0
__device__ __forceinline__ void tf_h1(uint32_t& x0, uint32_t& x1){ tf_h1g(0u,42u,0x1BD11BF0u,x0,x1); }
__device__ __forceinline__ void tf_h2(uint32_t& x0, uint32_t& x1){ tf_h2g(0u,42u,0x1BD11BF0u,x0,x1); }
#undef RND

// uniform(-0.99999994,1) -> sqrt(2)*erfinv (Giles poly, HW log) -> *0.05*0.5
__device__ __forceinline__ float bits_to_noise(uint32_t bits){
  float f = __uint_as_float((bits>>9) | 0x3F800000u) - 1.0f;
  const float lo = -0.99999994f;
  float x = fmaxf(fmaf(f, 1.99999994f, lo), lo);
  float m = (1.0f - x) * (1.0f + x);              // 1-x^2, cancellation-free
  float w = -0.69314718056f * __log2f(m);
  float p;
  if (w < 5.0f){
    w -= 2.5f;
    p = 2.81022636e-08f;
    p = fmaf(p, w, 3.43273939e-07f);
    p = fmaf(p, w, -3.5233877e-06f);
    p = fmaf(p, w, -4.39150654e-06f);
    p = fmaf(p, w, 0.00021858087f);
    p = fmaf(p, w, -0.00125372503f);
    p = fmaf(p, w, -0.00417768164f);
    p = fmaf(p, w, 0.246640727f);
    p = fmaf(p, w, 1.50140941f);
  } else {
    w = __fsqrt_rn(w) - 3.0f;
    p = -0.000200214257f;
    p = fmaf(p, w, 0.000100950558f);
    p = fmaf(p, w, 0.00134934322f);
    p = fmaf(p, w, -0.00367342844f);
    p = fmaf(p, w, 0.00573950773f);
    p = fmaf(p, w, -0.0076224613f);
    p = fmaf(p, w, 0.00943887047f);
    p = fmaf(p, w, 1.00167406f);
    p = fmaf(p, w, 2.83297682f);
  }
  return 0.035355339059f * (p * x);   // sqrt(2)*0.05*0.5
}

__global__ void init_flags(uint32_t* flags){
  if (flags) { flags[0]=0u; flags[1]=0u; }
}

__global__ void check_kernel(float* out, const uint32_t* flags){
  uint32_t a0=0u, a1=0u;                 tf2x32(0u,0u,a0,a1);
  uint32_t b0=0xffffffffu, b1=0xffffffffu; tf2x32(0xffffffffu,0xffffffffu,b0,b1);
  uint32_t c0=0x243f6a88u, c1=0x85a308d3u; tf2x32(0x13198a2eu,0x03707344u,c0,c1);
  if (!(a0==0x6b200159u && a1==0x99ba4efeu)) out[0] = 1e30f;
  if (!(b0==0x1cb996fcu && b1==0xbb002be7u)) out[1] = 2e30f;
  if (!(c0==0xc4923a9cu && c1==0x483df7a0u)) out[2] = 3e30f;
  uint32_t d0=7u, d1=9u; tf_h1(d0,d1); tf_h2(d0,d1);
  uint32_t e0=7u, e1=9u; tf2x32(0u,42u,e0,e1);
  if (!(d0==e0 && d1==e1)) out[3] = 4e30f;
  if (flags && flags[0]) out[5] = 6e30f;   // row entry-count overflow
}

__launch_bounds__(1024)
__global__ void rnn_kernel(const float* __restrict__ input_signal, // [B,T,2]
                           const float* __restrict__ hidden0,      // [B,H]
                           const float* __restrict__ w_in,         // [H,2]
                           const float* __restrict__ w_out,        // [2,H]
                           const float* __restrict__ abs_w0,       // [H,H]
                           const float* __restrict__ w_sign,       // [H,H]
                           const float* __restrict__ is_con,       // [H,H]
                           float* __restrict__ out,
                           uint32_t* __restrict__ flags)
{
  __shared__ float    ew[HB][NE];      // 48 KB  (init staging)
  __shared__ uint16_t ei[HB][NE];      // 24 KB  entry byte-offsets (rank*4)
  __shared__ float    xbuf[TT*2];      // 8 KB
  __shared__ float    hstage[8][HB];   // 8 KB   h staging (RANK-indexed)
  __shared__ float    nbuf[4][HB];     // 4 KB   noise ring (RANK-indexed)
  __shared__ float    tbuf[2][HB];     // 2 KB   tanh dbuf (RANK-indexed)
  __shared__ int      cnts[HB];
  __shared__ int      rankinv[HB];     // rank -> row
  __shared__ int      rof4[HB];        // row -> rank*4 (byte offset)
  __shared__ float    wot0[HB], wot1[HB];  // w_out in rank order

  const int tid = threadIdx.x;
  const int b   = blockIdx.x;
  const bool gw = (tid < 512);         // waves 0-7 gather; 8-15 noise/outproj

  // ---- P0: stage x + per-row counts ----
  {
    const float* xg = input_signal + (uint64_t)b*TT*2;
    *(float2*)(xbuf + tid*2) = *(const float2*)(xg + tid*2);
  }
  if (tid < HB){
    int c = 0;
    const float* ic = is_con + tid*HB;
    for (int k = 0; k < HB; k += 4){
      float4 c4 = *(const float4*)(ic + k);
      c += (c4.x>0.f)+(c4.y>0.f)+(c4.z>0.f)+(c4.w>0.f);
    }
    cnts[tid] = c;
    if (c > NE && flags) flags[0] = 1u;
  }
  __syncthreads();

  // ---- P1: ranks (descending count, tie by index) ----
  if (tid < HB){
    int myc = cnts[tid], r = 0;
    for (int k = 0; k < HB; ++k){
      int ck = cnts[k];
      r += (int)((ck > myc) || (ck == myc && k < tid));
    }
    rankinv[r] = tid;
    rof4[tid]  = r << 2;
  }
  __syncthreads();

  // ---- P2: build entry lists + wot scatter; noise prologue (de-lumped) ----
  uint32_t bj = 0u, ax0 = 0u, ax1 = 0u;
  if (tid < HB){
    const int j = tid;
    const float* ic = is_con + j*HB;
    const float* aw = abs_w0 + j*HB;
    const float* ws = w_sign + j*HB;
    int n = 0;
    for (int k = 0; k < HB; ++k){
      if (ic[k] > 0.f && n < NE){
        ew[j][n] = ws[k]*aw[k];
        ei[j][n] = (uint16_t)rof4[k];
        ++n;
      }
    }
    for (int s = n; s < NE; ++s){ ew[j][s] = 0.f; ei[j][s] = (uint16_t)rof4[j]; }
    wot0[rof4[j]>>2] = w_out[j];
    wot1[rof4[j]>>2] = w_out[HB + j];
  } else if (tid >= 512){
    int m2 = tid - 512, rn = m2 >> 1, qn = m2 & 1;
    bj = (uint32_t)b*256u + (uint32_t)rankinv[rn];
    if (qn == 0){                      // n(0) full
      uint32_t x0 = 0u, x1 = bj;
      tf2x32(0u, 42u, x0, x1);
      nbuf[0][rn] = bits_to_noise(x0 ^ x1);
    } else {                           // pre-start chain for n(1)
      ax0 = 0u; ax1 = 65536u + bj;
      tf_h1(ax0, ax1);
    }
  }
  __syncthreads();

  // ---- P3: pack registers ----
  float    pwv[NE2];                   // f32 weights (24 regs)
  uint32_t piv[NE2/2];                 // 2 u16 byte-offsets per reg (12 regs)
  int trip = 0, row = 0, q = 0, rr = 0;
  float h = 0.f, wi0 = 0.f, wi1 = 0.f;
  float4 wo0 = {0,0,0,0}, wo1 = {0,0,0,0};
  int rf0 = 0, rf1 = 0;
  const int j0 = (tid & 127) << 1;     // flush columns (all threads)
  rf0 = rof4[j0]; rf1 = rof4[j0+1];
  if (gw){
    rr = tid >> 1; q = tid & 1;
    row = rankinv[rr];
    int c = cnts[row]; if (c > NE) c = NE;
    uint32_t pad = (uint32_t)rof4[row];
    uint32_t cur = 0u;
    #pragma unroll
    for (int s = 0; s < NE2; ++s){
      int idx = 2*s + q;
      float w = 0.f; uint32_t o = pad;
      if (idx < c){ w = ew[row][idx]; o = ei[row][idx]; }
      pwv[s] = w;
      if (s & 1) piv[s>>1] = cur | (o << 16); else cur = o;
    }
    trip = __builtin_amdgcn_readfirstlane((c + 1) >> 1);  // lane0 = wave max (sorted)
    if (q == 0){
      h   = hidden0[b*HB + row];
      wi0 = w_in[row*2]; wi1 = w_in[row*2 + 1];
      tbuf[0][rr] = 1.0f - 2.0f/(__expf(2.0f*h) + 1.0f);
    }
  } else {
    int m2 = tid - 512;
    if (m2 < 128){
      int lam = m2 & 63;
      wo0 = *(const float4*)(wot0 + lam*4);
      wo1 = *(const float4*)(wot1 + lam*4);
    }
  }
  float* hrow = out + (uint64_t)b*TT*HB;
  float* orow = out + O1 + (uint64_t)b*TT*2;
  __syncthreads();

  // ---- main loop ----
  for (int t = 0; t < TT; ++t){
    const int par = t & 1;
    if (gw){
      const char* tb = (const char*)(&tbuf[par][0]);
      float y0 = 0.f, y1 = 0.f;
      // 3 groups x 8 entries: ONE wave-uniform guard per group -> 8 ds_reads
      // batch behind a single waitcnt inside each straight-line block.
      #pragma unroll
      for (int g = 0; g < 3; ++g){
        if (g*8 < trip){
          uint32_t a0 = piv[4*g+0], a1 = piv[4*g+1];
          uint32_t a2 = piv[4*g+2], a3 = piv[4*g+3];
          float t0 = *(const float*)(tb + (a0 & 0xFFFFu));
          float t1 = *(const float*)(tb + (a0 >> 16));
          float t2 = *(const float*)(tb + (a1 & 0xFFFFu));
          float t3 = *(const float*)(tb + (a1 >> 16));
          float t4 = *(const float*)(tb + (a2 & 0xFFFFu));
          float t5 = *(const float*)(tb + (a2 >> 16));
          float t6 = *(const float*)(tb + (a3 & 0xFFFFu));
          float t7 = *(const float*)(tb + (a3 >> 16));
          y0 = fmaf(pwv[8*g+0], t0, y0);
          y1 = fmaf(pwv[8*g+1], t1, y1);
          y0 = fmaf(pwv[8*g+2], t2, y0);
          y1 = fmaf(pwv[8*g+3], t3, y1);
          y0 = fmaf(pwv[8*g+4], t4, y0);
          y1 = fmaf(pwv[8*g+5], t5, y1);
          y0 = fmaf(pwv[8*g+6], t6, y0);
          y1 = fmaf(pwv[8*g+7], t7, y1);
        }
      }
      float y = y0 + y1;
      y += __shfl_xor(y, 1, 64);                 // combine row halves
      if (q == 0){
        float nz = nbuf[t&3][rr];
        float2 xv = *(const float2*)(xbuf + t*2);
        float u = fmaf(xv.x, wi0, xv.y*wi1);
        h = fmaf(0.25f, u + y, 0.75f*h) + nz;
        hstage[t&7][rr] = h;
        tbuf[par^1][rr] = 1.0f - 2.0f/(__expf(2.0f*h) + 1.0f);
      }
    } else {
      int m2 = tid - 512, rn = m2 >> 1, qn = m2 & 1;
      if (((t + 1) & 1) == qn){                  // finish n(t+1): rounds 13-20 + map
        if (t + 1 < TT){
          uint32_t f0 = ax0, f1 = ax1;
          tf_h2(f0, f1);
          nbuf[(t+1)&3][rn] = bits_to_noise(f0 ^ f1);
        }
      } else {                                   // start n(t+2): rounds 1-12
        if (t + 2 < TT){
          ax0 = 0u; ax1 = (uint32_t)(t+2)*65536u + bj;
          tf_h1(ax0, ax1);
        }
      }
      if (m2 < 128 && (t & 1)){                  // odd t: outproj o(t-2), o(t-1)
        int tau = t - 2 + (m2 >> 6);
        if (tau >= 0){
          int lam = m2 & 63;
          float4 hv = *(const float4*)(&hstage[tau&7][lam*4]);
          float p0 = hv.x*wo0.x + hv.y*wo0.y + hv.z*wo0.z + hv.w*wo0.w;
          float p1 = hv.x*wo1.x + hv.y*wo1.y + hv.z*wo1.z + hv.w*wo1.w;
          #pragma unroll
          for (int d = 1; d < 64; d <<= 1){
            p0 += __shfl_xor(p0, d, 64);
            p1 += __shfl_xor(p1, d, 64);
          }
          if (lam == 0) *(float2*)(orow + tau*2) = make_float2(p0, p1);
        }
      }
    }
    __syncthreads();                             // one barrier per step

    if ((t & 7) == 7){                           // coalesced flush (rank->natural)
      int s = tid >> 7;
      const char* hs = (const char*)(&hstage[s][0]);
      float2 v;
      v.x = *(const float*)(hs + rf0);
      v.y = *(const float*)(hs + rf1);
      *(float2*)(hrow + (uint64_t)(t - 7 + s)*HB + j0) = v;
    }
  }

  // ---- tail: o(1023) + h_last ----
  if (!gw){
    int m2 = tid - 512;
    if (m2 < 64){
      float4 hv = *(const float4*)(&hstage[7][m2*4]);
      float p0 = hv.x*wo0.x + hv.y*wo0.y + hv.z*wo0.z + hv.w*wo0.w;
      float p1 = hv.x*wo1.x + hv.y*wo1.y + hv.z*wo1.z + hv.w*wo1.w;
      #pragma unroll
      for (int d = 1; d < 64; d <<= 1){
        p0 += __shfl_xor(p0, d, 64);
        p1 += __shfl_xor(p1, d, 64);
      }
      if (m2 == 0) *(float2*)(orow + (TT-1)*2) = make_float2(p0, p1);
    }
  }
  if (gw && q == 0) out[O2 + b*HB + row] = h;
}

extern "C" void kernel_launch(void* const* d_in, const int* in_sizes, int n_in,
                              void* d_out, int out_size, void* d_ws, size_t ws_size,
                              hipStream_t stream) {
  const float* input_signal = (const float*)d_in[0];
  const float* hidden       = (const float*)d_in[1];
  const float* w_in         = (const float*)d_in[2];
  const float* w_out        = (const float*)d_in[3];
  const float* abs_w0       = (const float*)d_in[4];
  const float* w_sign       = (const float*)d_in[5];
  const float* is_con       = (const float*)d_in[6];
  float* out = (float*)d_out;
  uint32_t* flags = (ws_size >= 8) ? (uint32_t*)d_ws : nullptr;

  init_flags<<<1, 1, 0, stream>>>(flags);
  rnn_kernel<<<256, 1024, 0, stream>>>(input_signal, hidden, w_in, w_out,
                                       abs_w0, w_sign, is_con, out, flags);
  check_kernel<<<1, 1, 0, stream>>>(out, flags);
}